// Round 5
// baseline (440.749 us; speedup 1.0000x reference)
//
#include <hip/hip_runtime.h>

// Problem constants (reference shapes)
#define BQ 16
#define NP 4096
#define MP 4096

constexpr int TPB = 512;                        // 8 waves
constexpr int WAVES = 8;
constexpr int FR = 2;                           // B-fragments (32 sources) per wave
constexpr int SRC_PER_BLOCK = 32 * FR * WAVES;  // 512
constexpr int CHUNK = 512;                      // rows per LDS chunk (16 KB expanded)

typedef __bf16 bf16x8 __attribute__((ext_vector_type(8)));
typedef float f32x16 __attribute__((ext_vector_type(16)));

union Frag {
    unsigned short u[8];
    bf16x8 v;
    int4 i4;
};

// RNE float -> bf16 bits (no NaN inputs here)
__device__ inline unsigned short f2bf(float f) {
    unsigned u = __float_as_uint(f);
    return (unsigned short)((u + 0x7FFFu + ((u >> 16) & 1u)) >> 16);
}
__device__ inline float bf2f(unsigned short h) {
    return __uint_as_float(((unsigned)h) << 16);
}

__global__ void chamfer_zero_kernel(float* __restrict__ out) { out[0] = 0.0f; }

// ---------------------------------------------------------------------------
// Single fused MFMA chamfer kernel. grid = (NP/SRC_PER_BLOCK, 2*BQ) = (8, 32)
// = 256 blocks (1/CU, 2 waves/SIMD).
// d2(i,j) = K=13 bf16 dot product (hi/lo split, bit-exact-verified in R3):
// rows (A) stream through double-buffered LDS; each wave holds FR=2 fixed
// B-fragments (64 source columns), so each A-frag ds_read_b128 feeds 2 MFMAs.
// The 16 C-regs per MFMA are 16 rows of one column -> in-lane min3 tree
// (8 min3 / 1024 pairs, the VALU floor), xor-32 fold, clamp, block sum,
// one weighted atomicAdd per block. Block covers ALL rows for its columns,
// so there is no cross-block min combine and no workspace.
// ---------------------------------------------------------------------------
__global__ __launch_bounds__(TPB) void chamfer_mfma_kernel(
    const float* __restrict__ srcp,   // [BQ][NP][3]
    const float* __restrict__ tgtp,   // [BQ][MP][3]
    const float* __restrict__ wts,    // [BQ]
    float* __restrict__ out)          // scalar
{
    const int gy  = blockIdx.y;
    const int dir = gy >> 4;
    const int b   = gy & 15;
    // dir0: cols(B)=src points, rows(A)=tgt points; dir1: swapped.
    const float* S = dir ? (tgtp + (size_t)b * MP * 3) : (srcp + (size_t)b * NP * 3);
    const float* T = dir ? (srcp + (size_t)b * NP * 3) : (tgtp + (size_t)b * MP * 3);

    const int tid  = threadIdx.x;
    const int lane = tid & 63;
    const int half = lane >> 5;   // K-half selector for A/B operands
    const int col  = lane & 31;
    const int wave = tid >> 6;

    // [2 buffers][16 sub-chunks][2 halves][32 rows][8 shorts]
    // A-read: lane stride 16 B within a (sub,half) plane -> conflict-free
    // (phase covers all 32 banks; R3 measured SQ_LDS_BANK_CONFLICT = 0).
    __shared__ unsigned short sh[2][CHUNK * 16];
    __shared__ float partial[WAVES];

    const unsigned short ONE = 0x3F80;  // bf16(1.0)

    // ---- FR fixed B-fragments (source side) ----
    Frag bfr[FR];
#pragma unroll
    for (int f = 0; f < FR; ++f) {
        const int sidx = blockIdx.x * SRC_PER_BLOCK + (wave * FR + f) * 32 + col;
        const float* sp = S + (size_t)sidx * 3;
        float x = sp[0], y = sp[1], z = sp[2];
        unsigned short uh0 = f2bf(-2.0f * x), uh1 = f2bf(-2.0f * y), uh2 = f2bf(-2.0f * z);
        unsigned short ul0 = f2bf(-2.0f * x - bf2f(uh0));
        unsigned short ul1 = f2bf(-2.0f * y - bf2f(uh1));
        unsigned short ul2 = f2bf(-2.0f * z - bf2f(uh2));
        float s2 = fmaf(x, x, fmaf(y, y, z * z));
        unsigned short s2h = f2bf(s2), s2l = f2bf(s2 - bf2f(s2h));
        if (half == 0) {  // k = 0..7
            bfr[f].u[0] = uh0; bfr[f].u[1] = uh1; bfr[f].u[2] = uh2;
            bfr[f].u[3] = ul0; bfr[f].u[4] = ul1; bfr[f].u[5] = ul2;
            bfr[f].u[6] = uh0; bfr[f].u[7] = uh1;
        } else {          // k = 8..15
            bfr[f].u[0] = uh2; bfr[f].u[1] = ONE; bfr[f].u[2] = ONE;
            bfr[f].u[3] = s2h; bfr[f].u[4] = s2l;
            bfr[f].u[5] = 0;   bfr[f].u[6] = 0;  bfr[f].u[7] = 0;
        }
    }

    // Expand one row point into its two 16B K-planes and store at this
    // thread's slot in buffer `pb` (thread t <-> chunk row t).
    const int sub = tid >> 5, row = tid & 31;
    auto expand_write = [&](int pb, float x, float y, float z) {
        unsigned short xh = f2bf(x), yh = f2bf(y), zh = f2bf(z);
        unsigned short xl = f2bf(x - bf2f(xh));
        unsigned short yl = f2bf(y - bf2f(yh));
        unsigned short zl = f2bf(z - bf2f(zh));
        float t2 = fmaf(x, x, fmaf(y, y, z * z));
        unsigned short t2h = f2bf(t2), t2l = f2bf(t2 - bf2f(t2h));
        Frag p0, p1;
        p0.u[0] = xh; p0.u[1] = yh; p0.u[2] = zh;   // k0..2: hi  (x -2s hi)
        p0.u[3] = xh; p0.u[4] = yh; p0.u[5] = zh;   // k3..5: hi  (x -2s lo)
        p0.u[6] = xl; p0.u[7] = yl;                 // k6..7: lo x,y (x -2s hi)
        p1.u[0] = zl;                               // k8:    lo z
        p1.u[1] = t2h; p1.u[2] = t2l;               // k9..10: t2 (x 1)
        p1.u[3] = ONE; p1.u[4] = ONE;               // k11..12: 1 (x s2 hi/lo)
        p1.u[5] = 0; p1.u[6] = 0; p1.u[7] = 0;
        *(int4*)&sh[pb][((sub * 2 + 0) * 32 + row) * 8] = p0.i4;
        *(int4*)&sh[pb][((sub * 2 + 1) * 32 + row) * 8] = p1.i4;
    };

    // Preload + expand chunk 0.
    {
        const float* tp = T + (size_t)tid * 3;
        expand_write(0, tp[0], tp[1], tp[2]);
    }
    __syncthreads();

    float accm[FR];
#pragma unroll
    for (int f = 0; f < FR; ++f) accm[f] = __int_as_float(0x7F800000);

    const f32x16 zc = {};

    for (int c = 0; c < MP / CHUNK; ++c) {  // 8 chunks of 512 rows
        // Issue next chunk's global loads before compute (latency hiding).
        float nx = 0.f, ny = 0.f, nz = 0.f;
        const bool hasnext = (c + 1 < MP / CHUNK);
        if (hasnext) {
            const float* tp = T + (size_t)((c + 1) * CHUNK + tid) * 3;
            nx = tp[0]; ny = tp[1]; nz = tp[2];
        }

        const unsigned short* buf = sh[c & 1];
#pragma unroll
        for (int sc = 0; sc < 16; ++sc) {
            Frag a;
            a.i4 = *(const int4*)&buf[((sc * 2 + half) * 32 + col) * 8];
#pragma unroll
            for (int f = 0; f < FR; ++f) {
                f32x16 d = __builtin_amdgcn_mfma_f32_32x32x16_bf16(a.v, bfr[f].v, zc, 0, 0, 0);
                float m0 = fminf(fminf(d[0], d[1]), d[2]);
                float m1 = fminf(fminf(d[3], d[4]), d[5]);
                float m2 = fminf(fminf(d[6], d[7]), d[8]);
                float m3 = fminf(fminf(d[9], d[10]), d[11]);
                float m4 = fminf(fminf(d[12], d[13]), d[14]);
                float t0 = fminf(fminf(m0, m1), m2);
                float t1 = fminf(fminf(m3, m4), d[15]);
                accm[f] = fminf(fminf(accm[f], t0), t1);
            }
        }

        if (hasnext) expand_write((c + 1) & 1, nx, ny, nz);
        __syncthreads();  // protects buf[(c+1)&1] writes vs next-iter reads,
                          // and buf[c&1] reads vs iter c+1's writes to it
    }

    // ---- epilogue: fold row-halves, clamp, sum this wave's 64 columns ----
    float tot = 0.0f;
#pragma unroll
    for (int f = 0; f < FR; ++f) {
        float m = fminf(accm[f], __shfl_xor(accm[f], 32, 64));
        tot += fmaxf(m, 0.0f);
    }
#pragma unroll
    for (int off = 32; off > 0; off >>= 1) tot += __shfl_xor(tot, off, 64);
    if (lane == 0) partial[wave] = tot * 0.5f;  // each column counted twice
    __syncthreads();
    if (tid == 0) {
        float v = 0.0f;
#pragma unroll
        for (int w = 0; w < WAVES; ++w) v += partial[w];
        atomicAdd(out, v * wts[b] * (1.0f / ((float)NP * (float)BQ)));
    }
}

// ---------------------------------------------------------------------------
extern "C" void kernel_launch(void* const* d_in, const int* in_sizes, int n_in,
                              void* d_out, int out_size, void* d_ws, size_t ws_size,
                              hipStream_t stream) {
    const float* src = (const float*)d_in[0];
    const float* tgt = (const float*)d_in[1];
    const float* wts = (const float*)d_in[2];
    float* out = (float*)d_out;

    chamfer_zero_kernel<<<1, 1, 0, stream>>>(out);

    dim3 grid(NP / SRC_PER_BLOCK, 2 * BQ);  // (8, 32) = 256 blocks
    chamfer_mfma_kernel<<<grid, TPB, 0, stream>>>(src, tgt, wts, out);
}

// Round 6
// 91.132 us; speedup vs baseline: 4.8364x; 4.8364x over previous
//
#include <hip/hip_runtime.h>

// Problem constants (reference shapes)
#define BQ 16
#define NP 4096
#define MP 4096

constexpr int TPB = 256;                        // 4 waves (R5 lesson: NOT 512)
constexpr int WAVES = 4;
constexpr int FR = 2;                           // B-fragments (32 cols) per wave
constexpr int SRC_PER_BLOCK = 32 * FR * WAVES;  // 256 columns per block
constexpr int CHUNK = 256;                      // rows per LDS chunk (8 KB expanded)

typedef __bf16 bf16x8 __attribute__((ext_vector_type(8)));
typedef float f32x16 __attribute__((ext_vector_type(16)));

union Frag {
    unsigned short u[8];
    bf16x8 v;
    int4 i4;
};

// RNE float -> bf16 bits (no NaN inputs here)
__device__ inline unsigned short f2bf(float f) {
    unsigned u = __float_as_uint(f);
    return (unsigned short)((u + 0x7FFFu + ((u >> 16) & 1u)) >> 16);
}
__device__ inline float bf2f(unsigned short h) {
    return __uint_as_float(((unsigned)h) << 16);
}

__global__ void chamfer_zero_kernel(float* __restrict__ out) { out[0] = 0.0f; }

// ---------------------------------------------------------------------------
// Single fused MFMA chamfer kernel. grid = (NP/SRC_PER_BLOCK, 2*BQ) = (16, 32)
// = 512 blocks (2/CU, 8 waves/CU).
// d2(i,j) = K=13 bf16 dot (hi/lo split, bit-exact-verified R3): rows (A)
// stream through an 8 KB LDS buffer; each wave holds FR=2 fixed B-fragments
// (64 source columns), so each A-frag ds_read_b128 feeds 2 MFMAs and the
// per-(dir,b) row-expansion redundancy is 16x (R3: 32x) -- expansion was the
// largest VALU term. 16 C-regs per MFMA = 16 rows of one column -> in-lane
// min3 tree, xor-32 fold, clamp, block sum, one weighted atomicAdd.
// No d_ws use (ws re-poison fill costs ~43 us in the timed stream).
// ---------------------------------------------------------------------------
__global__ __launch_bounds__(TPB) void chamfer_mfma_kernel(
    const float* __restrict__ srcp,   // [BQ][NP][3]
    const float* __restrict__ tgtp,   // [BQ][MP][3]
    const float* __restrict__ wts,    // [BQ]
    float* __restrict__ out)          // scalar
{
    const int gy  = blockIdx.y;
    const int dir = gy >> 4;
    const int b   = gy & 15;
    // dir0: cols(B)=src points, rows(A)=tgt points; dir1: swapped.
    const float* S = dir ? (tgtp + (size_t)b * MP * 3) : (srcp + (size_t)b * NP * 3);
    const float* T = dir ? (srcp + (size_t)b * NP * 3) : (tgtp + (size_t)b * MP * 3);

    const int tid  = threadIdx.x;
    const int lane = tid & 63;
    const int half = lane >> 5;   // K-half selector for A/B operands
    const int col  = lane & 31;
    const int wave = tid >> 6;

    // [8 sub][2 half][32 row][8 short] = 8 KB; A-read lane-stride 16 B within
    // a (sub,half) plane -> conflict-free (R3 measured SQ_LDS_BANK_CONFLICT=0)
    __shared__ unsigned short sh[CHUNK * 16];
    __shared__ float partial[WAVES];

    const unsigned short ONE = 0x3F80;  // bf16(1.0)

    // ---- FR fixed B-fragments (source side) ----
    Frag bfr[FR];
#pragma unroll
    for (int f = 0; f < FR; ++f) {
        const int sidx = blockIdx.x * SRC_PER_BLOCK + (wave * FR + f) * 32 + col;
        const float* sp = S + (size_t)sidx * 3;
        float x = sp[0], y = sp[1], z = sp[2];
        unsigned short uh0 = f2bf(-2.0f * x), uh1 = f2bf(-2.0f * y), uh2 = f2bf(-2.0f * z);
        unsigned short ul0 = f2bf(-2.0f * x - bf2f(uh0));
        unsigned short ul1 = f2bf(-2.0f * y - bf2f(uh1));
        unsigned short ul2 = f2bf(-2.0f * z - bf2f(uh2));
        float s2 = fmaf(x, x, fmaf(y, y, z * z));
        unsigned short s2h = f2bf(s2), s2l = f2bf(s2 - bf2f(s2h));
        if (half == 0) {  // k = 0..7
            bfr[f].u[0] = uh0; bfr[f].u[1] = uh1; bfr[f].u[2] = uh2;
            bfr[f].u[3] = ul0; bfr[f].u[4] = ul1; bfr[f].u[5] = ul2;
            bfr[f].u[6] = uh0; bfr[f].u[7] = uh1;
        } else {          // k = 8..15
            bfr[f].u[0] = uh2; bfr[f].u[1] = ONE; bfr[f].u[2] = ONE;
            bfr[f].u[3] = s2h; bfr[f].u[4] = s2l;
            bfr[f].u[5] = 0;   bfr[f].u[6] = 0;  bfr[f].u[7] = 0;
        }
    }

    float accm[FR];
#pragma unroll
    for (int f = 0; f < FR; ++f) accm[f] = __int_as_float(0x7F800000);

    const f32x16 zc = {};
    const int sub = tid >> 5, row = tid & 31;

    // Preload chunk 0's row point.
    float cx, cy, cz;
    {
        const float* tp = T + (size_t)tid * 3;
        cx = tp[0]; cy = tp[1]; cz = tp[2];
    }

    for (int c = 0; c < MP / CHUNK; ++c) {  // 16 chunks of 256 rows
        // ---- stage: expand this thread's row into its two 16B K-planes ----
        {
            unsigned short xh = f2bf(cx), yh = f2bf(cy), zh = f2bf(cz);
            unsigned short xl = f2bf(cx - bf2f(xh));
            unsigned short yl = f2bf(cy - bf2f(yh));
            unsigned short zl = f2bf(cz - bf2f(zh));
            float t2 = fmaf(cx, cx, fmaf(cy, cy, cz * cz));
            unsigned short t2h = f2bf(t2), t2l = f2bf(t2 - bf2f(t2h));
            Frag p0, p1;
            p0.u[0] = xh; p0.u[1] = yh; p0.u[2] = zh;   // k0..2: hi  (x -2s hi)
            p0.u[3] = xh; p0.u[4] = yh; p0.u[5] = zh;   // k3..5: hi  (x -2s lo)
            p0.u[6] = xl; p0.u[7] = yl;                 // k6..7: lo x,y (x -2s hi)
            p1.u[0] = zl;                               // k8:    lo z
            p1.u[1] = t2h; p1.u[2] = t2l;               // k9..10: t2 (x 1)
            p1.u[3] = ONE; p1.u[4] = ONE;               // k11..12: 1 (x s2 hi/lo)
            p1.u[5] = 0; p1.u[6] = 0; p1.u[7] = 0;
            *(int4*)&sh[((sub * 2 + 0) * 32 + row) * 8] = p0.i4;
            *(int4*)&sh[((sub * 2 + 1) * 32 + row) * 8] = p1.i4;
        }
        __syncthreads();

        // Issue next chunk's global load now; consumed after the barrier at
        // the top of the next iteration (hidden under this chunk's compute).
        if (c + 1 < MP / CHUNK) {
            const float* tp = T + (size_t)((c + 1) * CHUNK + tid) * 3;
            cx = tp[0]; cy = tp[1]; cz = tp[2];
        }

        // ---- 8 sub-chunks; each A-fragment feeds FR=2 MFMAs ----
#pragma unroll
        for (int sc = 0; sc < CHUNK / 32; ++sc) {
            Frag a;
            a.i4 = *(const int4*)&sh[((sc * 2 + half) * 32 + col) * 8];
#pragma unroll
            for (int f = 0; f < FR; ++f) {
                f32x16 d = __builtin_amdgcn_mfma_f32_32x32x16_bf16(a.v, bfr[f].v, zc, 0, 0, 0);
                float m0 = fminf(fminf(d[0], d[1]), d[2]);
                float m1 = fminf(fminf(d[3], d[4]), d[5]);
                float m2 = fminf(fminf(d[6], d[7]), d[8]);
                float m3 = fminf(fminf(d[9], d[10]), d[11]);
                float m4 = fminf(fminf(d[12], d[13]), d[14]);
                float t0 = fminf(fminf(m0, m1), m2);
                float t1 = fminf(fminf(m3, m4), d[15]);
                accm[f] = fminf(fminf(accm[f], t0), t1);
            }
        }
        __syncthreads();
    }

    // ---- epilogue: fold row-halves, clamp, sum this wave's 64 columns ----
    float tot = 0.0f;
#pragma unroll
    for (int f = 0; f < FR; ++f) {
        float m = fminf(accm[f], __shfl_xor(accm[f], 32, 64));
        tot += fmaxf(m, 0.0f);
    }
#pragma unroll
    for (int off = 32; off > 0; off >>= 1) tot += __shfl_xor(tot, off, 64);
    if (lane == 0) partial[wave] = tot * 0.5f;  // each column counted twice
    __syncthreads();
    if (tid == 0) {
        float v = partial[0] + partial[1] + partial[2] + partial[3];
        atomicAdd(out, v * wts[b] * (1.0f / ((float)NP * (float)BQ)));
    }
}

// ---------------------------------------------------------------------------
extern "C" void kernel_launch(void* const* d_in, const int* in_sizes, int n_in,
                              void* d_out, int out_size, void* d_ws, size_t ws_size,
                              hipStream_t stream) {
    const float* src = (const float*)d_in[0];
    const float* tgt = (const float*)d_in[1];
    const float* wts = (const float*)d_in[2];
    float* out = (float*)d_out;

    chamfer_zero_kernel<<<1, 1, 0, stream>>>(out);

    dim3 grid(NP / SRC_PER_BLOCK, 2 * BQ);  // (16, 32) = 512 blocks
    chamfer_mfma_kernel<<<grid, TPB, 0, stream>>>(src, tgt, wts, out);
}